// Round 10
// baseline (295.667 us; speedup 1.0000x reference)
//
#include <hip/hip_runtime.h>

// Problem constants (fixed by the reference setup_inputs)
#define B_SZ 2
#define T_SZ 2048
#define DM   1024
#define NH   16
#define DH   64
#define MROWS (B_SZ * T_SZ)   // 4096

typedef unsigned short u16;
typedef short  s16x8 __attribute__((ext_vector_type(8)));   // 8 bf16 (4 VGPRs)
typedef float  f32x4 __attribute__((ext_vector_type(4)));   // MFMA C/D

// fp32 -> bf16 round-to-nearest-even
static __device__ __forceinline__ u16 f2bf(float x) {
  unsigned u = __float_as_uint(x);
  u += 0x7fffu + ((u >> 16) & 1u);
  return (u16)(u >> 16);
}

// ---------------------------------------------------------------------------
// z=0/1: Wt[n][k] = bf16(W[k][n]) for Wq/Wk. z=2: zero ctx (262144 f32).
// grid (16,16,3).
// ---------------------------------------------------------------------------
__global__ __launch_bounds__(256)
void k_cvt_T2(const float* __restrict__ Wq, const float* __restrict__ Wk,
              u16* __restrict__ Wqt, u16* __restrict__ Wkt,
              float* __restrict__ ctx) {
  if (blockIdx.z == 2) {
    int idx = (blockIdx.x + 16 * blockIdx.y) * 256 + threadIdx.x;  // 65536
    ((float4*)ctx)[idx] = make_float4(0.f, 0.f, 0.f, 0.f);
    return;
  }
  const float* W = blockIdx.z ? Wk : Wq;
  u16* Wt = blockIdx.z ? Wkt : Wqt;
  __shared__ u16 t[64][72];
  const int n0 = blockIdx.x * 64, k0 = blockIdx.y * 64;
  const int tid = threadIdx.x;
#pragma unroll
  for (int e = 0; e < 4; ++e) {
    int c = tid + e * 256;
    int k = c >> 4, n4 = c & 15;
    float4 v = *(const float4*)(W + (size_t)(k0 + k) * DM + n0 + n4 * 4);
    t[n4 * 4 + 0][k] = f2bf(v.x);
    t[n4 * 4 + 1][k] = f2bf(v.y);
    t[n4 * 4 + 2][k] = f2bf(v.z);
    t[n4 * 4 + 3][k] = f2bf(v.w);
  }
  __syncthreads();
#pragma unroll
  for (int e = 0; e < 2; ++e) {
    int c = tid + e * 256;
    int n = c >> 3, c16 = c & 7;
    *(uint4*)(Wt + (size_t)(n0 + n) * DM + k0 + c16 * 8) = *(const uint4*)&t[n][c16 * 8];
  }
}

// ---------------------------------------------------------------------------
// Merged projection GEMM with fused A-side f32->bf16 convert.
// GRID (32 m, 8 n, 2 z): blocks sharing an A row-band have ID%8 == m%8 ->
// same XCD -> A band served from that XCD's L2 (R9-verified win).
// ---------------------------------------------------------------------------
__global__ __launch_bounds__(256)
void gemm_qk(const float* __restrict__ qf, const float* __restrict__ kf,
             const u16* __restrict__ Wqt, const u16* __restrict__ Wkt,
             u16* __restrict__ Qp, u16* __restrict__ Kp, float qscale) {
  const int z = blockIdx.z;
  const float* A = z ? kf : qf;
  const u16* Bt = z ? Wkt : Wqt;
  u16* C = z ? Kp : Qp;
  const float scale = z ? 1.0f : qscale;

  __shared__ u16 As[128][40];
  __shared__ u16 Bs[128][40];
  const int tid = threadIdx.x;
  const int lane = tid & 63, w = tid >> 6;
  const int l15 = lane & 15, q4 = lane >> 4;
  const int wm = w & 1, wn = w >> 1;
  const int m0 = blockIdx.x * 128, n0 = blockIdx.y * 128;   // x=m for XCD share

  f32x4 acc[4][4] = {};

  for (int k0 = 0; k0 < DM; k0 += 32) {
    __syncthreads();
#pragma unroll
    for (int e = 0; e < 4; ++e) {
      int c = tid + e * 256;
      int row = c >> 3, c4 = c & 7;
      float4 av = *(const float4*)(A + (size_t)(m0 + row) * DM + k0 + c4 * 4);
      ushort4 o;
      o.x = f2bf(av.x); o.y = f2bf(av.y); o.z = f2bf(av.z); o.w = f2bf(av.w);
      *(ushort4*)&As[row][c4 * 4] = o;
    }
#pragma unroll
    for (int e = 0; e < 2; ++e) {
      int c = tid + e * 256;
      int row = c >> 2, c16 = c & 3;
      *(uint4*)&Bs[row][c16 * 8] = *(const uint4*)(Bt + (size_t)(n0 + row) * DM + k0 + c16 * 8);
    }
    __syncthreads();
    s16x8 a[4], b[4];
#pragma unroll
    for (int mi = 0; mi < 4; ++mi) a[mi] = *(const s16x8*)&As[wm * 64 + mi * 16 + l15][q4 * 8];
#pragma unroll
    for (int ni = 0; ni < 4; ++ni) b[ni] = *(const s16x8*)&Bs[wn * 64 + ni * 16 + l15][q4 * 8];
#pragma unroll
    for (int mi = 0; mi < 4; ++mi)
#pragma unroll
      for (int ni = 0; ni < 4; ++ni)
        acc[mi][ni] = __builtin_amdgcn_mfma_f32_16x16x32_bf16(a[mi], b[ni], acc[mi][ni], 0, 0, 0);
  }
#pragma unroll
  for (int mi = 0; mi < 4; ++mi)
#pragma unroll
    for (int ni = 0; ni < 4; ++ni)
#pragma unroll
      for (int r = 0; r < 4; ++r) {
        int m = m0 + wm * 64 + mi * 16 + q4 * 4 + r;
        int n = n0 + wn * 64 + ni * 16 + l15;
        C[(size_t)m * DM + n] = f2bf(acc[mi][ni][r] * scale);
      }
}

// ---------------------------------------------------------------------------
// Pass 1 v6 (R9-proven): block (x,h,b) handles q-tiles x and 31-x. Rounds of
// 128 k-cols. Transient K staging (no spill). Q pre-scaled by 0.125*log2e.
// ---------------------------------------------------------------------------
__global__ __launch_bounds__(256)
void attn_sums_v6(const u16* __restrict__ Qb, const u16* __restrict__ Kb,
                  float* __restrict__ invL) {
  __shared__ u16 Ks[128][72];
  __shared__ float red[64][17];
  const int x = blockIdx.x, h = blockIdx.y, b = blockIdx.z;
  const int tid = threadIdx.x;
  const int lane = tid & 63, w = tid >> 6;
  const int l15 = lane & 15, q4 = lane >> 4;

  const int qts[2] = {x, 31 - x};
  s16x8 qf[2][2];
#pragma unroll
  for (int s = 0; s < 2; ++s) {
    const u16* Qbase = Qb + ((size_t)(b * T_SZ + qts[s] * 64)) * DM + h * DH;
    __syncthreads();
#pragma unroll
    for (int e = 0; e < 2; ++e) {
      int lin = tid + e * 256;
      int row = lin >> 3, c8 = lin & 7;
      *(uint4*)&Ks[row][c8 * 8] = *(const uint4*)(Qbase + (size_t)row * DM + c8 * 8);
    }
    __syncthreads();
    qf[s][0] = *(const s16x8*)&Ks[w * 16 + l15][q4 * 8];
    qf[s][1] = *(const s16x8*)&Ks[w * 16 + l15][32 + q4 * 8];
  }

  float part[2][4] = {};
  const int last = 31 - x;
  const int R = (last + 2) >> 1;

  const u16* Kbase = Kb + ((size_t)b * T_SZ) * DM + h * DH;

  for (int r = 0; r < R; ++r) {
    __syncthreads();
#pragma unroll
    for (int e = 0; e < 4; ++e) {
      int lin = tid + e * 256;
      int row = lin >> 3, c8 = lin & 7;
      *(uint4*)&Ks[row][c8 * 8] =
          *(const uint4*)(Kbase + (size_t)(r * 128 + row) * DM + c8 * 8);
    }
    __syncthreads();
#pragma unroll
    for (int ktl = 0; ktl < 2; ++ktl) {
      const int kt = r * 2 + ktl;
      if (kt > last) continue;
#pragma unroll
      for (int s = 0; s < 2; ++s) {
        if (kt > qts[s]) continue;
        f32x4 sacc[4] = {};
#pragma unroll
        for (int ni = 0; ni < 4; ++ni) {
          s16x8 b0 = *(const s16x8*)&Ks[ktl * 64 + ni * 16 + l15][q4 * 8];
          s16x8 b1 = *(const s16x8*)&Ks[ktl * 64 + ni * 16 + l15][32 + q4 * 8];
          sacc[ni] = __builtin_amdgcn_mfma_f32_16x16x32_bf16(qf[s][0], b0, sacc[ni], 0, 0, 0);
          sacc[ni] = __builtin_amdgcn_mfma_f32_16x16x32_bf16(qf[s][1], b1, sacc[ni], 0, 0, 0);
        }
        const bool diag = (kt == qts[s]);
#pragma unroll
        for (int ni = 0; ni < 4; ++ni)
#pragma unroll
          for (int rr = 0; rr < 4; ++rr) {
            int row_l = w * 16 + q4 * 4 + rr;
            int col_l = ni * 16 + l15;
            bool ok = !diag || (col_l <= row_l);
            part[s][rr] += ok ? __builtin_amdgcn_exp2f(sacc[ni][rr]) : 0.f;
          }
      }
    }
  }

#pragma unroll
  for (int s = 0; s < 2; ++s) {
    __syncthreads();
#pragma unroll
    for (int rr = 0; rr < 4; ++rr) red[w * 16 + q4 * 4 + rr][l15] = part[s][rr];
    __syncthreads();
    if (tid < 64) {
      float sum = 0.f;
#pragma unroll
      for (int t = 0; t < 16; ++t) sum += red[tid][t];
      invL[((size_t)(b * NH + h)) * T_SZ + qts[s] * 64 + tid] = 1.0f / sum;
    }
  }
}

// ---------------------------------------------------------------------------
// Pass 2 v7: R5-proven 64(q) x 256(k) strip + FUSED PV.
// After the head loop the block holds the normalized attn tile in registers:
// write it to global (output 2) AND round-trip bf16 through LDS (reusing Ks)
// as MFMA A-fragments, multiply by V^T (bf16, L2-resident), atomicAdd the
// 64x64 ctx partial. Eliminates the separate ctx_part kernel.
// ---------------------------------------------------------------------------
__global__ __launch_bounds__(256)
void attn_write_v7(const u16* __restrict__ Qb, const u16* __restrict__ Kb,
                   const float* __restrict__ invL, const u16* __restrict__ Vt,
                   float* __restrict__ ctx, float* __restrict__ attn) {
  const int c = blockIdx.x, qt = blockIdx.y, b = blockIdx.z;
  const int tid = threadIdx.x;
  float* outp = attn + ((size_t)b * T_SZ + (size_t)qt * 64) * T_SZ + c * 256;

  if (4 * c > qt) {            // whole strip above diagonal: zeros, no ctx
    float4 z = make_float4(0.f, 0.f, 0.f, 0.f);
#pragma unroll
    for (int e = 0; e < 16; ++e) {
      int lin = tid + e * 256;
      int i = lin >> 6, c4 = lin & 63;
      *(float4*)(outp + (size_t)i * T_SZ + c4 * 4) = z;
    }
    return;
  }

  __shared__ u16 Qs[64][72];
  __shared__ u16 Ks[256][72];   // phase 2 reuses this as P[64][264] bf16
  __shared__ float Ls[16][64];
  const int lane = tid & 63, w = tid >> 6;
  const int l15 = lane & 15, q4 = lane >> 4;

  {  // stage invL for all heads once
    int hh = tid >> 4, r4 = tid & 15;
    *(float4*)&Ls[hh][r4 * 4] =
        *(const float4*)(invL + ((size_t)(b * NH + hh)) * T_SZ + qt * 64 + r4 * 4);
  }

  const u16* Qrow = Qb + ((size_t)(b * T_SZ + qt * 64)) * DM;
  const u16* Krow = Kb + ((size_t)(b * T_SZ + c * 256)) * DM;

  f32x4 acc[4][4] = {};   // [ktl][ni]

  for (int h = 0; h < NH; ++h) {
    __syncthreads();
    const int hoff = h * DH;
#pragma unroll
    for (int e = 0; e < 2; ++e) {   // Q: 512 x 16B chunks
      int cc = tid + e * 256;
      int row = cc >> 3, c8 = cc & 7;
      *(uint4*)&Qs[row][c8 * 8] = *(const uint4*)(Qrow + (size_t)row * DM + hoff + c8 * 8);
    }
#pragma unroll
    for (int e = 0; e < 8; ++e) {   // K: 2048 x 16B chunks (4 tiles stacked)
      int cc = tid + e * 256;
      int row = cc >> 3, c8 = cc & 7;
      *(uint4*)&Ks[row][c8 * 8] = *(const uint4*)(Krow + (size_t)row * DM + hoff + c8 * 8);
    }
    __syncthreads();
    s16x8 aq0 = *(const s16x8*)&Qs[w * 16 + l15][q4 * 8];
    s16x8 aq1 = *(const s16x8*)&Qs[w * 16 + l15][32 + q4 * 8];
#pragma unroll
    for (int ktl = 0; ktl < 4; ++ktl) {
      const int kt = 4 * c + ktl;
      if (kt > qt) continue;        // uniform; acc stays zero
      f32x4 s[4] = {};
#pragma unroll
      for (int ni = 0; ni < 4; ++ni) {
        s16x8 b0 = *(const s16x8*)&Ks[ktl * 64 + ni * 16 + l15][q4 * 8];
        s16x8 b1 = *(const s16x8*)&Ks[ktl * 64 + ni * 16 + l15][32 + q4 * 8];
        s[ni] = __builtin_amdgcn_mfma_f32_16x16x32_bf16(aq0, b0, s[ni], 0, 0, 0);
        s[ni] = __builtin_amdgcn_mfma_f32_16x16x32_bf16(aq1, b1, s[ni], 0, 0, 0);
      }
      if (kt == qt) {
#pragma unroll
        for (int ni = 0; ni < 4; ++ni)
#pragma unroll
          for (int r = 0; r < 4; ++r) {
            int row_l = w * 16 + q4 * 4 + r;
            int col_l = ni * 16 + l15;
            float ev = __builtin_amdgcn_exp2f(s[ni][r]) * Ls[h][row_l];
            if (col_l <= row_l) acc[ktl][ni][r] += ev;
          }
      } else {
#pragma unroll
        for (int ni = 0; ni < 4; ++ni)
#pragma unroll
          for (int r = 0; r < 4; ++r) {
            int row_l = w * 16 + q4 * 4 + r;
            acc[ktl][ni][r] += __builtin_amdgcn_exp2f(s[ni][r]) * Ls[h][row_l];
          }
      }
    }
  }

  // ---- write normalized attn tile to global + P (bf16) to LDS ----
  __syncthreads();               // all waves done with Ks as K storage
  u16* Ps = &Ks[0][0];           // reuse as P[64][264] (row stride 264 u16)
#pragma unroll
  for (int ktl = 0; ktl < 4; ++ktl)
#pragma unroll
    for (int ni = 0; ni < 4; ++ni)
#pragma unroll
      for (int r = 0; r < 4; ++r) {
        int row_l = w * 16 + q4 * 4 + r;
        int col_l = ktl * 64 + ni * 16 + l15;
        float pv = acc[ktl][ni][r] * 0.0625f;
        outp[(size_t)row_l * T_SZ + col_l] = pv;
        Ps[row_l * 264 + col_l] = f2bf(pv);
      }
  __syncthreads();

  // ---- PV: ctx[qt*64 + m][n] += P(64x256) @ V(256x64) via MFMA ----
  s16x8 pa[8];
#pragma unroll
  for (int kc = 0; kc < 8; ++kc)
    pa[kc] = *(const s16x8*)&Ps[(w * 16 + l15) * 264 + kc * 32 + q4 * 8];

  const u16* Vt_b = Vt + (size_t)b * DH * T_SZ;   // [64][2048]
  f32x4 cacc[4] = {};
#pragma unroll
  for (int ni = 0; ni < 4; ++ni) {
#pragma unroll
    for (int kc = 0; kc < 8; ++kc) {
      s16x8 vb = *(const s16x8*)(Vt_b + (size_t)(ni * 16 + l15) * T_SZ +
                                 c * 256 + kc * 32 + q4 * 8);
      cacc[ni] = __builtin_amdgcn_mfma_f32_16x16x32_bf16(pa[kc], vb, cacc[ni], 0, 0, 0);
    }
  }
  float* ctx_qb = ctx + ((size_t)(b * T_SZ + qt * 64)) * DH;
#pragma unroll
  for (int ni = 0; ni < 4; ++ni)
#pragma unroll
    for (int r = 0; r < 4; ++r)
      atomicAdd(&ctx_qb[(size_t)(w * 16 + q4 * 4 + r) * DH + ni * 16 + l15],
                cacc[ni][r]);
}

// ---------------------------------------------------------------------------
// V projection -> bf16 V^T: Vt[b][col][t] = bf16((v @ Wv)[b*2048+t][col]).
// One block per 16 rows (256 blocks); transpose through LDS.
// ---------------------------------------------------------------------------
__global__ __launch_bounds__(256)
void proj_v(const float* __restrict__ A, const float* __restrict__ W,
            u16* __restrict__ Vt) {
  __shared__ float Ws[64][68];
  __shared__ float As[16][68];
  __shared__ float tr[64][17];
  const int tid = threadIdx.x;
  const int m0 = blockIdx.x * 16;
  const int row = tid >> 4;
  const int c4  = tid & 15;
  float4 acc = make_float4(0.f, 0.f, 0.f, 0.f);

  for (int k0 = 0; k0 < DM; k0 += 64) {
    __syncthreads();
#pragma unroll
    for (int e = 0; e < 4; ++e) {
      int lin = tid + e * 256;
      int r = lin >> 4, cc = lin & 15;
      *(float4*)&Ws[r][cc * 4] = *(const float4*)(W + (size_t)(k0 + r) * DH + cc * 4);
    }
    *(float4*)&As[row][c4 * 4] = *(const float4*)(A + (size_t)(m0 + row) * DM + k0 + c4 * 4);
    __syncthreads();
#pragma unroll
    for (int kk = 0; kk < 64; ++kk) {
      float a = As[row][kk];
      float4 wv = *(const float4*)&Ws[kk][c4 * 4];
      acc.x += a * wv.x; acc.y += a * wv.y; acc.z += a * wv.z; acc.w += a * wv.w;
    }
  }
  __syncthreads();
  tr[c4 * 4 + 0][row] = acc.x;
  tr[c4 * 4 + 1][row] = acc.y;
  tr[c4 * 4 + 2][row] = acc.z;
  tr[c4 * 4 + 3][row] = acc.w;
  __syncthreads();
  // write out: 64 cols x 16 t, ushort4 per thread
  const int b = m0 >> 11;            // m0 / 2048
  const int t0 = m0 & 2047;
  int col = tid >> 2, tc = tid & 3;
  ushort4 o;
  o.x = f2bf(tr[col][tc * 4 + 0]);
  o.y = f2bf(tr[col][tc * 4 + 1]);
  o.z = f2bf(tr[col][tc * 4 + 2]);
  o.w = f2bf(tr[col][tc * 4 + 3]);
  *(ushort4*)(Vt + ((size_t)b * DH + col) * T_SZ + t0 + tc * 4) = o;
}

// ---------------------------------------------------------------------------
// Wo projection: out[4096][1024] = ctx[4096][64] @ Wo[64][1024]. fp32.
// GRID (32 m, 8 n) — m on x for XCD-local ctx reuse.
// ---------------------------------------------------------------------------
__global__ __launch_bounds__(256)
void gemm_wo(const float* __restrict__ ctx, const float* __restrict__ W,
             float* __restrict__ C) {
  __shared__ float As[16][132];
  __shared__ float Ws[16][132];
  const int tid = threadIdx.x;
  const int tx = tid & 15, ty = tid >> 4;
  const int m0 = blockIdx.x * 128;
  const int n0 = blockIdx.y * 128;

  float acc[8][8];
#pragma unroll
  for (int i = 0; i < 8; ++i)
#pragma unroll
    for (int j = 0; j < 8; ++j) acc[i][j] = 0.f;

  for (int k0 = 0; k0 < DH; k0 += 16) {
    __syncthreads();
#pragma unroll
    for (int e = 0; e < 2; ++e) {
      int lin = tid + e * 256;
      int i = lin >> 2, j4 = lin & 3;
      float4 p = *(const float4*)(ctx + (size_t)(m0 + i) * DH + k0 + j4 * 4);
      As[j4 * 4 + 0][i] = p.x;
      As[j4 * 4 + 1][i] = p.y;
      As[j4 * 4 + 2][i] = p.z;
      As[j4 * 4 + 3][i] = p.w;
    }
#pragma unroll
    for (int e = 0; e < 2; ++e) {
      int lin = tid + e * 256;
      int kk = lin >> 5, n4 = lin & 31;
      *(float4*)&Ws[kk][n4 * 4] = *(const float4*)(W + (size_t)(k0 + kk) * DM + n0 + n4 * 4);
    }
    __syncthreads();
#pragma unroll
    for (int kk = 0; kk < 16; ++kk) {
      float4 a0 = *(const float4*)&As[kk][ty * 8];
      float4 a1 = *(const float4*)&As[kk][ty * 8 + 4];
      float4 b0 = *(const float4*)&Ws[kk][tx * 8];
      float4 b1 = *(const float4*)&Ws[kk][tx * 8 + 4];
      float a[8] = {a0.x, a0.y, a0.z, a0.w, a1.x, a1.y, a1.z, a1.w};
      float b[8] = {b0.x, b0.y, b0.z, b0.w, b1.x, b1.y, b1.z, b1.w};
#pragma unroll
      for (int i = 0; i < 8; ++i)
#pragma unroll
        for (int j = 0; j < 8; ++j) acc[i][j] += a[i] * b[j];
    }
  }
#pragma unroll
  for (int i = 0; i < 8; ++i) {
    size_t m = (size_t)(m0 + ty * 8 + i);
    int n = n0 + tx * 8;
    *(float4*)(C + m * DM + n) = make_float4(acc[i][0], acc[i][1], acc[i][2], acc[i][3]);
    *(float4*)(C + m * DM + n + 4) = make_float4(acc[i][4], acc[i][5], acc[i][6], acc[i][7]);
  }
}

// ---------------------------------------------------------------------------
extern "C" void kernel_launch(void* const* d_in, const int* in_sizes, int n_in,
                              void* d_out, int out_size, void* d_ws, size_t ws_size,
                              hipStream_t stream) {
  (void)in_sizes; (void)n_in; (void)out_size; (void)ws_size;

  const float* q  = (const float*)d_in[0];
  const float* k  = (const float*)d_in[1];
  const float* v  = (const float*)d_in[2];
  // d_in[3] is the causal tril mask; causality applied analytically.
  const float* Wq = (const float*)d_in[4];
  const float* Wk = (const float*)d_in[5];
  const float* Wv = (const float*)d_in[6];
  const float* Wo = (const float*)d_in[7];

  float* out  = (float*)d_out;                      // [4096][1024]
  float* attn = out + (size_t)MROWS * DM;           // [2][2048][2048]

  // Workspace (~22.5 MB)
  u16*   Qb   = (u16*)d_ws;                         // [4096][1024] bf16 (Q pre-scaled by 0.125*log2e)
  u16*   Kb   = Qb + (size_t)MROWS * DM;
  u16*   Wqt  = Kb + (size_t)MROWS * DM;            // [1024][1024] bf16 (W^T)
  u16*   Wkt  = Wqt + (size_t)DM * DM;
  u16*   Vt   = Wkt + (size_t)DM * DM;              // [2][64][2048] bf16 (V^T)
  float* invL = (float*)(Vt + (size_t)B_SZ * DH * T_SZ);  // [2][16][2048] f32
  float* ctx  = invL + (size_t)B_SZ * NH * T_SZ;    // [4096][64] f32 (atomic acc)

  dim3 thr(256, 1, 1);

  k_cvt_T2<<<dim3(DM / 64, DM / 64, 3), thr, 0, stream>>>(Wq, Wk, Wqt, Wkt, ctx);

  // Q pre-scaled so prob = exp2(score): scale = 0.125 * log2(e)
  const float qscale = 0.125f * 1.44269504088896340736f;
  gemm_qk<<<dim3(MROWS / 128, DM / 128, 2), thr, 0, stream>>>(q, k, Wqt, Wkt, Qb, Kb, qscale);
  proj_v<<<MROWS / 16, thr, 0, stream>>>(v, Wv, Vt);

  attn_sums_v6<<<dim3(16, NH, B_SZ), thr, 0, stream>>>(Qb, Kb, invL);
  attn_write_v7<<<dim3(8, 32, B_SZ), thr, 0, stream>>>(Qb, Kb, invL, Vt, ctx, attn);

  gemm_wo<<<dim3(MROWS / 128, DM / 128), thr, 0, stream>>>(ctx, Wo, out);
}

// Round 11
// 277.382 us; speedup vs baseline: 1.0659x; 1.0659x over previous
//
#include <hip/hip_runtime.h>

// Problem constants (fixed by the reference setup_inputs)
#define B_SZ 2
#define T_SZ 2048
#define DM   1024
#define NH   16
#define DH   64
#define MROWS (B_SZ * T_SZ)   // 4096
#define CTX_CH 8              // split-K chunks for the ctx matmul

typedef unsigned short u16;
typedef short  s16x8 __attribute__((ext_vector_type(8)));   // 8 bf16 (4 VGPRs)
typedef float  f32x4 __attribute__((ext_vector_type(4)));   // MFMA C/D

// fp32 -> bf16 round-to-nearest-even
static __device__ __forceinline__ u16 f2bf(float x) {
  unsigned u = __float_as_uint(x);
  u += 0x7fffu + ((u >> 16) & 1u);
  return (u16)(u >> 16);
}

// ---------------------------------------------------------------------------
// Wt[n][k] = bf16(W[k][n]) for Wq/Wk (z selects). grid (16,16,2).
// ---------------------------------------------------------------------------
__global__ __launch_bounds__(256)
void k_cvt_T2(const float* __restrict__ Wq, const float* __restrict__ Wk,
              u16* __restrict__ Wqt, u16* __restrict__ Wkt) {
  const float* W = blockIdx.z ? Wk : Wq;
  u16* Wt = blockIdx.z ? Wkt : Wqt;
  __shared__ u16 t[64][72];
  const int n0 = blockIdx.x * 64, k0 = blockIdx.y * 64;
  const int tid = threadIdx.x;
#pragma unroll
  for (int e = 0; e < 4; ++e) {
    int c = tid + e * 256;
    int k = c >> 4, n4 = c & 15;
    float4 v = *(const float4*)(W + (size_t)(k0 + k) * DM + n0 + n4 * 4);
    t[n4 * 4 + 0][k] = f2bf(v.x);
    t[n4 * 4 + 1][k] = f2bf(v.y);
    t[n4 * 4 + 2][k] = f2bf(v.z);
    t[n4 * 4 + 3][k] = f2bf(v.w);
  }
  __syncthreads();
#pragma unroll
  for (int e = 0; e < 2; ++e) {
    int c = tid + e * 256;
    int n = c >> 3, c16 = c & 7;
    *(uint4*)(Wt + (size_t)(n0 + n) * DM + k0 + c16 * 8) = *(const uint4*)&t[n][c16 * 8];
  }
}

// ---------------------------------------------------------------------------
// Merged projection GEMM with fused A-side f32->bf16 convert.
// GRID (32 m, 8 n, 2 z): blocks sharing an A row-band have ID%8 == m%8 ->
// same XCD -> A band served from that XCD's L2 (R9-verified win).
// ---------------------------------------------------------------------------
__global__ __launch_bounds__(256)
void gemm_qk(const float* __restrict__ qf, const float* __restrict__ kf,
             const u16* __restrict__ Wqt, const u16* __restrict__ Wkt,
             u16* __restrict__ Qp, u16* __restrict__ Kp, float qscale) {
  const int z = blockIdx.z;
  const float* A = z ? kf : qf;
  const u16* Bt = z ? Wkt : Wqt;
  u16* C = z ? Kp : Qp;
  const float scale = z ? 1.0f : qscale;

  __shared__ u16 As[128][40];
  __shared__ u16 Bs[128][40];
  const int tid = threadIdx.x;
  const int lane = tid & 63, w = tid >> 6;
  const int l15 = lane & 15, q4 = lane >> 4;
  const int wm = w & 1, wn = w >> 1;
  const int m0 = blockIdx.x * 128, n0 = blockIdx.y * 128;   // x=m for XCD share

  f32x4 acc[4][4] = {};

  for (int k0 = 0; k0 < DM; k0 += 32) {
    __syncthreads();
#pragma unroll
    for (int e = 0; e < 4; ++e) {
      int c = tid + e * 256;
      int row = c >> 3, c4 = c & 7;
      float4 av = *(const float4*)(A + (size_t)(m0 + row) * DM + k0 + c4 * 4);
      ushort4 o;
      o.x = f2bf(av.x); o.y = f2bf(av.y); o.z = f2bf(av.z); o.w = f2bf(av.w);
      *(ushort4*)&As[row][c4 * 4] = o;
    }
#pragma unroll
    for (int e = 0; e < 2; ++e) {
      int c = tid + e * 256;
      int row = c >> 2, c16 = c & 3;
      *(uint4*)&Bs[row][c16 * 8] = *(const uint4*)(Bt + (size_t)(n0 + row) * DM + k0 + c16 * 8);
    }
    __syncthreads();
    s16x8 a[4], b[4];
#pragma unroll
    for (int mi = 0; mi < 4; ++mi) a[mi] = *(const s16x8*)&As[wm * 64 + mi * 16 + l15][q4 * 8];
#pragma unroll
    for (int ni = 0; ni < 4; ++ni) b[ni] = *(const s16x8*)&Bs[wn * 64 + ni * 16 + l15][q4 * 8];
#pragma unroll
    for (int mi = 0; mi < 4; ++mi)
#pragma unroll
      for (int ni = 0; ni < 4; ++ni)
        acc[mi][ni] = __builtin_amdgcn_mfma_f32_16x16x32_bf16(a[mi], b[ni], acc[mi][ni], 0, 0, 0);
  }
#pragma unroll
  for (int mi = 0; mi < 4; ++mi)
#pragma unroll
    for (int ni = 0; ni < 4; ++ni)
#pragma unroll
      for (int r = 0; r < 4; ++r) {
        int m = m0 + wm * 64 + mi * 16 + q4 * 4 + r;
        int n = n0 + wn * 64 + ni * 16 + l15;
        C[(size_t)m * DM + n] = f2bf(acc[mi][ni][r] * scale);
      }
}

// ---------------------------------------------------------------------------
// Pass 1 v6 (R9-proven): block (x,h,b) handles q-tiles x and 31-x. Rounds of
// 128 k-cols. Transient K staging (no spill). Q pre-scaled by 0.125*log2e.
// ---------------------------------------------------------------------------
__global__ __launch_bounds__(256)
void attn_sums_v6(const u16* __restrict__ Qb, const u16* __restrict__ Kb,
                  float* __restrict__ invL) {
  __shared__ u16 Ks[128][72];
  __shared__ float red[64][17];
  const int x = blockIdx.x, h = blockIdx.y, b = blockIdx.z;
  const int tid = threadIdx.x;
  const int lane = tid & 63, w = tid >> 6;
  const int l15 = lane & 15, q4 = lane >> 4;

  const int qts[2] = {x, 31 - x};
  s16x8 qf[2][2];
#pragma unroll
  for (int s = 0; s < 2; ++s) {
    const u16* Qbase = Qb + ((size_t)(b * T_SZ + qts[s] * 64)) * DM + h * DH;
    __syncthreads();
#pragma unroll
    for (int e = 0; e < 2; ++e) {
      int lin = tid + e * 256;
      int row = lin >> 3, c8 = lin & 7;
      *(uint4*)&Ks[row][c8 * 8] = *(const uint4*)(Qbase + (size_t)row * DM + c8 * 8);
    }
    __syncthreads();
    qf[s][0] = *(const s16x8*)&Ks[w * 16 + l15][q4 * 8];
    qf[s][1] = *(const s16x8*)&Ks[w * 16 + l15][32 + q4 * 8];
  }

  float part[2][4] = {};
  const int last = 31 - x;
  const int R = (last + 2) >> 1;

  const u16* Kbase = Kb + ((size_t)b * T_SZ) * DM + h * DH;

  for (int r = 0; r < R; ++r) {
    __syncthreads();
#pragma unroll
    for (int e = 0; e < 4; ++e) {
      int lin = tid + e * 256;
      int row = lin >> 3, c8 = lin & 7;
      *(uint4*)&Ks[row][c8 * 8] =
          *(const uint4*)(Kbase + (size_t)(r * 128 + row) * DM + c8 * 8);
    }
    __syncthreads();
#pragma unroll
    for (int ktl = 0; ktl < 2; ++ktl) {
      const int kt = r * 2 + ktl;
      if (kt > last) continue;
#pragma unroll
      for (int s = 0; s < 2; ++s) {
        if (kt > qts[s]) continue;
        f32x4 sacc[4] = {};
#pragma unroll
        for (int ni = 0; ni < 4; ++ni) {
          s16x8 b0 = *(const s16x8*)&Ks[ktl * 64 + ni * 16 + l15][q4 * 8];
          s16x8 b1 = *(const s16x8*)&Ks[ktl * 64 + ni * 16 + l15][32 + q4 * 8];
          sacc[ni] = __builtin_amdgcn_mfma_f32_16x16x32_bf16(qf[s][0], b0, sacc[ni], 0, 0, 0);
          sacc[ni] = __builtin_amdgcn_mfma_f32_16x16x32_bf16(qf[s][1], b1, sacc[ni], 0, 0, 0);
        }
        const bool diag = (kt == qts[s]);
#pragma unroll
        for (int ni = 0; ni < 4; ++ni)
#pragma unroll
          for (int rr = 0; rr < 4; ++rr) {
            int row_l = w * 16 + q4 * 4 + rr;
            int col_l = ni * 16 + l15;
            bool ok = !diag || (col_l <= row_l);
            part[s][rr] += ok ? __builtin_amdgcn_exp2f(sacc[ni][rr]) : 0.f;
          }
      }
    }
  }

#pragma unroll
  for (int s = 0; s < 2; ++s) {
    __syncthreads();
#pragma unroll
    for (int rr = 0; rr < 4; ++rr) red[w * 16 + q4 * 4 + rr][l15] = part[s][rr];
    __syncthreads();
    if (tid < 64) {
      float sum = 0.f;
#pragma unroll
      for (int t = 0; t < 16; ++t) sum += red[tid][t];
      invL[((size_t)(b * NH + h)) * T_SZ + qts[s] * 64 + tid] = 1.0f / sum;
    }
  }
}

// ---------------------------------------------------------------------------
// Pass 2 (R5/R9-proven): block (c, qt, b) owns a 64(q) x 256(k) strip.
// ---------------------------------------------------------------------------
__global__ __launch_bounds__(256)
void attn_write_v3(const u16* __restrict__ Qb, const u16* __restrict__ Kb,
                   const float* __restrict__ invL, float* __restrict__ attn) {
  const int c = blockIdx.x, qt = blockIdx.y, b = blockIdx.z;
  const int tid = threadIdx.x;
  float* outp = attn + ((size_t)b * T_SZ + (size_t)qt * 64) * T_SZ + c * 256;

  if (4 * c > qt) {            // whole strip above diagonal
    float4 z = make_float4(0.f, 0.f, 0.f, 0.f);
#pragma unroll
    for (int e = 0; e < 16; ++e) {
      int lin = tid + e * 256;
      int i = lin >> 6, c4 = lin & 63;
      *(float4*)(outp + (size_t)i * T_SZ + c4 * 4) = z;
    }
    return;
  }

  __shared__ u16 Qs[64][72];
  __shared__ u16 Ks[256][72];
  __shared__ float Ls[16][64];
  const int lane = tid & 63, w = tid >> 6;
  const int l15 = lane & 15, q4 = lane >> 4;

  {  // stage invL for all heads once
    int hh = tid >> 4, r4 = tid & 15;
    *(float4*)&Ls[hh][r4 * 4] =
        *(const float4*)(invL + ((size_t)(b * NH + hh)) * T_SZ + qt * 64 + r4 * 4);
  }

  const u16* Qrow = Qb + ((size_t)(b * T_SZ + qt * 64)) * DM;
  const u16* Krow = Kb + ((size_t)(b * T_SZ + c * 256)) * DM;

  f32x4 acc[4][4] = {};   // [ktl][ni]

  for (int h = 0; h < NH; ++h) {
    __syncthreads();
    const int hoff = h * DH;
#pragma unroll
    for (int e = 0; e < 2; ++e) {   // Q: 512 x 16B chunks
      int cc = tid + e * 256;
      int row = cc >> 3, c8 = cc & 7;
      *(uint4*)&Qs[row][c8 * 8] = *(const uint4*)(Qrow + (size_t)row * DM + hoff + c8 * 8);
    }
#pragma unroll
    for (int e = 0; e < 8; ++e) {   // K: 2048 x 16B chunks (4 tiles stacked)
      int cc = tid + e * 256;
      int row = cc >> 3, c8 = cc & 7;
      *(uint4*)&Ks[row][c8 * 8] = *(const uint4*)(Krow + (size_t)row * DM + hoff + c8 * 8);
    }
    __syncthreads();
    s16x8 aq0 = *(const s16x8*)&Qs[w * 16 + l15][q4 * 8];
    s16x8 aq1 = *(const s16x8*)&Qs[w * 16 + l15][32 + q4 * 8];
#pragma unroll
    for (int ktl = 0; ktl < 4; ++ktl) {
      const int kt = 4 * c + ktl;
      if (kt > qt) continue;        // uniform; acc stays zero -> writes zeros
      f32x4 s[4] = {};
#pragma unroll
      for (int ni = 0; ni < 4; ++ni) {
        s16x8 b0 = *(const s16x8*)&Ks[ktl * 64 + ni * 16 + l15][q4 * 8];
        s16x8 b1 = *(const s16x8*)&Ks[ktl * 64 + ni * 16 + l15][32 + q4 * 8];
        s[ni] = __builtin_amdgcn_mfma_f32_16x16x32_bf16(aq0, b0, s[ni], 0, 0, 0);
        s[ni] = __builtin_amdgcn_mfma_f32_16x16x32_bf16(aq1, b1, s[ni], 0, 0, 0);
      }
      if (kt == qt) {
#pragma unroll
        for (int ni = 0; ni < 4; ++ni)
#pragma unroll
          for (int r = 0; r < 4; ++r) {
            int row_l = w * 16 + q4 * 4 + r;
            int col_l = ni * 16 + l15;
            float ev = __builtin_amdgcn_exp2f(s[ni][r]) * Ls[h][row_l];
            if (col_l <= row_l) acc[ktl][ni][r] += ev;
          }
      } else {
#pragma unroll
        for (int ni = 0; ni < 4; ++ni)
#pragma unroll
          for (int r = 0; r < 4; ++r) {
            int row_l = w * 16 + q4 * 4 + r;
            acc[ktl][ni][r] += __builtin_amdgcn_exp2f(s[ni][r]) * Ls[h][row_l];
          }
      }
    }
  }
#pragma unroll
  for (int ktl = 0; ktl < 4; ++ktl)
#pragma unroll
    for (int ni = 0; ni < 4; ++ni)
#pragma unroll
      for (int r = 0; r < 4; ++r)
        outp[(size_t)(w * 16 + q4 * 4 + r) * T_SZ + ktl * 64 + ni * 16 + l15] =
            acc[ktl][ni][r] * 0.0625f;
}

// ---------------------------------------------------------------------------
// V projection -> bf16 V^T: Vt[b][col][t] = bf16((v @ Wv)[b*2048+t][col]).
// One block per 16 rows (256 blocks); transpose through LDS. (R10-verified)
// ---------------------------------------------------------------------------
__global__ __launch_bounds__(256)
void proj_v(const float* __restrict__ A, const float* __restrict__ W,
            u16* __restrict__ Vt) {
  __shared__ float Ws[64][68];
  __shared__ float As[16][68];
  __shared__ float tr[64][17];
  const int tid = threadIdx.x;
  const int m0 = blockIdx.x * 16;
  const int row = tid >> 4;
  const int c4  = tid & 15;
  float4 acc = make_float4(0.f, 0.f, 0.f, 0.f);

  for (int k0 = 0; k0 < DM; k0 += 64) {
    __syncthreads();
#pragma unroll
    for (int e = 0; e < 4; ++e) {
      int lin = tid + e * 256;
      int r = lin >> 4, cc = lin & 15;
      *(float4*)&Ws[r][cc * 4] = *(const float4*)(W + (size_t)(k0 + r) * DH + cc * 4);
    }
    *(float4*)&As[row][c4 * 4] = *(const float4*)(A + (size_t)(m0 + row) * DM + k0 + c4 * 4);
    __syncthreads();
#pragma unroll
    for (int kk = 0; kk < 64; ++kk) {
      float a = As[row][kk];
      float4 wv = *(const float4*)&Ws[kk][c4 * 4];
      acc.x += a * wv.x; acc.y += a * wv.y; acc.z += a * wv.z; acc.w += a * wv.w;
    }
  }
  __syncthreads();
  tr[c4 * 4 + 0][row] = acc.x;
  tr[c4 * 4 + 1][row] = acc.y;
  tr[c4 * 4 + 2][row] = acc.z;
  tr[c4 * 4 + 3][row] = acc.w;
  __syncthreads();
  const int b = m0 >> 11;
  const int t0 = m0 & 2047;
  int col = tid >> 2, tc = tid & 3;
  ushort4 o;
  o.x = f2bf(tr[col][tc * 4 + 0]);
  o.y = f2bf(tr[col][tc * 4 + 1]);
  o.z = f2bf(tr[col][tc * 4 + 2]);
  o.w = f2bf(tr[col][tc * 4 + 3]);
  *(ushort4*)(Vt + ((size_t)b * DH + col) * T_SZ + t0 + tc * 4) = o;
}

// ---------------------------------------------------------------------------
// ctx split-K partials via bf16 MFMA. Block (c, mt, b): rows mt*64..+63,
// k in [c*256, c*256+255], two 128-k chunks. attn staged f32->bf16 into Pc
// (coalesced row reads); Vt strip staged into Vc (rows contiguous in t).
// Both LDS reads match MFMA fragment layout -> no strided global access
// (fixes R10's uncoalesced Vt loads). Always writes its partial (poisoned
// buffer); upper-triangle attn regions are zeros so they contribute 0.
// ---------------------------------------------------------------------------
__global__ __launch_bounds__(256)
void ctx_part_mfma(const float* __restrict__ attn, const u16* __restrict__ Vt,
                   float* __restrict__ part) {
  __shared__ u16 Pc[64][136];
  __shared__ u16 Vc[64][136];
  const int c = blockIdx.x, mt = blockIdx.y, b = blockIdx.z;
  const int tid = threadIdx.x;
  const int lane = tid & 63, w = tid >> 6;
  const int l15 = lane & 15, q4 = lane >> 4;

  const float* attn_b = attn + ((size_t)b * T_SZ + (size_t)mt * 64) * T_SZ;
  const u16* Vt_b = Vt + (size_t)b * DH * T_SZ;

  f32x4 acc[4] = {};   // wave's 16 m-rows x 64 n-cols

  if (4 * c <= mt) {   // strip intersects the causal region
#pragma unroll
    for (int ch = 0; ch < 2; ++ch) {
      const int k0 = c * 256 + ch * 128;
      if (k0 > mt * 64 + 63) continue;   // chunk fully above diagonal
      __syncthreads();
      // stage attn chunk: 64 rows x 128 f32 -> bf16 (2048 float4, 8/thread)
#pragma unroll
      for (int e = 0; e < 8; ++e) {
        int lin = tid + e * 256;
        int row = lin >> 5, c4 = lin & 31;
        float4 av = *(const float4*)(attn_b + (size_t)row * T_SZ + k0 + c4 * 4);
        ushort4 o;
        o.x = f2bf(av.x); o.y = f2bf(av.y); o.z = f2bf(av.z); o.w = f2bf(av.w);
        *(ushort4*)&Pc[row][c4 * 4] = o;
      }
      // stage Vt strip: 64 cols x 128 t (1024 uint4, 4/thread, coalesced)
#pragma unroll
      for (int e = 0; e < 4; ++e) {
        int lin = tid + e * 256;
        int col = lin >> 4, c8 = lin & 15;
        *(uint4*)&Vc[col][c8 * 8] =
            *(const uint4*)(Vt_b + (size_t)col * T_SZ + k0 + c8 * 8);
      }
      __syncthreads();
      // wave w: rows w*16..+15; 4 ni x 4 kc MFMAs
#pragma unroll
      for (int kc = 0; kc < 4; ++kc) {
        s16x8 pa = *(const s16x8*)&Pc[w * 16 + l15][kc * 32 + q4 * 8];
#pragma unroll
        for (int ni = 0; ni < 4; ++ni) {
          s16x8 vb = *(const s16x8*)&Vc[ni * 16 + l15][kc * 32 + q4 * 8];
          acc[ni] = __builtin_amdgcn_mfma_f32_16x16x32_bf16(pa, vb, acc[ni], 0, 0, 0);
        }
      }
    }
  }

  float* pp = part + (((size_t)c * B_SZ + b) * T_SZ + (size_t)mt * 64) * DH;
#pragma unroll
  for (int ni = 0; ni < 4; ++ni)
#pragma unroll
    for (int r = 0; r < 4; ++r)
      pp[(size_t)(w * 16 + q4 * 4 + r) * DH + ni * 16 + l15] = acc[ni][r];
}

// ---------------------------------------------------------------------------
// Wo projection with fused split-K reduce. GRID (32 m, 8 n): blocks sharing
// the reduced A-band land on the same XCD (ID%8 == m%8).
// ---------------------------------------------------------------------------
__global__ __launch_bounds__(256)
void gemm_wo(const float* __restrict__ part, const float* __restrict__ W,
             float* __restrict__ C) {
  __shared__ float As[16][132];
  __shared__ float Ws[16][132];
  const int tid = threadIdx.x;
  const int tx = tid & 15, ty = tid >> 4;
  const int m0 = blockIdx.x * 128;   // x=m for XCD share
  const int n0 = blockIdx.y * 128;

  float acc[8][8];
#pragma unroll
  for (int i = 0; i < 8; ++i)
#pragma unroll
    for (int j = 0; j < 8; ++j) acc[i][j] = 0.f;

  for (int k0 = 0; k0 < DH; k0 += 16) {
    __syncthreads();
#pragma unroll
    for (int e = 0; e < 2; ++e) {
      int lin = tid + e * 256;
      int i = lin >> 2, j4 = lin & 3;
      float4 s = make_float4(0.f, 0.f, 0.f, 0.f);
#pragma unroll
      for (int cc = 0; cc < CTX_CH; ++cc) {
        float4 p = *(const float4*)(part + (size_t)cc * MROWS * DH +
                                    (size_t)(m0 + i) * DH + k0 + j4 * 4);
        s.x += p.x; s.y += p.y; s.z += p.z; s.w += p.w;
      }
      As[j4 * 4 + 0][i] = s.x;
      As[j4 * 4 + 1][i] = s.y;
      As[j4 * 4 + 2][i] = s.z;
      As[j4 * 4 + 3][i] = s.w;
    }
#pragma unroll
    for (int e = 0; e < 2; ++e) {
      int lin = tid + e * 256;
      int kk = lin >> 5, n4 = lin & 31;
      *(float4*)&Ws[kk][n4 * 4] = *(const float4*)(W + (size_t)(k0 + kk) * DM + n0 + n4 * 4);
    }
    __syncthreads();
#pragma unroll
    for (int kk = 0; kk < 16; ++kk) {
      float4 a0 = *(const float4*)&As[kk][ty * 8];
      float4 a1 = *(const float4*)&As[kk][ty * 8 + 4];
      float4 b0 = *(const float4*)&Ws[kk][tx * 8];
      float4 b1 = *(const float4*)&Ws[kk][tx * 8 + 4];
      float a[8] = {a0.x, a0.y, a0.z, a0.w, a1.x, a1.y, a1.z, a1.w};
      float b[8] = {b0.x, b0.y, b0.z, b0.w, b1.x, b1.y, b1.z, b1.w};
#pragma unroll
      for (int i = 0; i < 8; ++i)
#pragma unroll
        for (int j = 0; j < 8; ++j) acc[i][j] += a[i] * b[j];
    }
  }
#pragma unroll
  for (int i = 0; i < 8; ++i) {
    size_t m = (size_t)(m0 + ty * 8 + i);
    int n = n0 + tx * 8;
    *(float4*)(C + m * DM + n) = make_float4(acc[i][0], acc[i][1], acc[i][2], acc[i][3]);
    *(float4*)(C + m * DM + n + 4) = make_float4(acc[i][4], acc[i][5], acc[i][6], acc[i][7]);
  }
}

// ---------------------------------------------------------------------------
extern "C" void kernel_launch(void* const* d_in, const int* in_sizes, int n_in,
                              void* d_out, int out_size, void* d_ws, size_t ws_size,
                              hipStream_t stream) {
  (void)in_sizes; (void)n_in; (void)out_size; (void)ws_size;

  const float* q  = (const float*)d_in[0];
  const float* k  = (const float*)d_in[1];
  const float* v  = (const float*)d_in[2];
  // d_in[3] is the causal tril mask; causality applied analytically.
  const float* Wq = (const float*)d_in[4];
  const float* Wk = (const float*)d_in[5];
  const float* Wv = (const float*)d_in[6];
  const float* Wo = (const float*)d_in[7];

  float* out  = (float*)d_out;                      // [4096][1024]
  float* attn = out + (size_t)MROWS * DM;           // [2][2048][2048]

  // Workspace (~30 MB)
  u16*   Qb   = (u16*)d_ws;                         // [4096][1024] bf16 (Q pre-scaled by 0.125*log2e)
  u16*   Kb   = Qb + (size_t)MROWS * DM;
  u16*   Wqt  = Kb + (size_t)MROWS * DM;            // [1024][1024] bf16 (W^T)
  u16*   Wkt  = Wqt + (size_t)DM * DM;
  u16*   Vt   = Wkt + (size_t)DM * DM;              // [2][64][2048] bf16 (V^T)
  float* invL = (float*)(Vt + (size_t)B_SZ * DH * T_SZ);  // [2][16][2048] f32
  float* part = invL + (size_t)B_SZ * NH * T_SZ;    // [8][4096][64] f32 (8.4 MB)

  dim3 thr(256, 1, 1);

  k_cvt_T2<<<dim3(DM / 64, DM / 64, 2), thr, 0, stream>>>(Wq, Wk, Wqt, Wkt);

  // Q pre-scaled so prob = exp2(score): scale = 0.125 * log2(e)
  const float qscale = 0.125f * 1.44269504088896340736f;
  gemm_qk<<<dim3(MROWS / 128, DM / 128, 2), thr, 0, stream>>>(q, k, Wqt, Wkt, Qb, Kb, qscale);
  proj_v<<<MROWS / 16, thr, 0, stream>>>(v, Wv, Vt);

  attn_sums_v6<<<dim3(16, NH, B_SZ), thr, 0, stream>>>(Qb, Kb, invL);
  attn_write_v3<<<dim3(8, 32, B_SZ), thr, 0, stream>>>(Qb, Kb, invL, attn);

  ctx_part_mfma<<<dim3(CTX_CH, T_SZ / 64, B_SZ), thr, 0, stream>>>(attn, Vt, part);
  gemm_wo<<<dim3(MROWS / 128, DM / 128), thr, 0, stream>>>(part, Wo, out);
}